// Round 1
// 1052.974 us; speedup vs baseline: 1.0122x; 1.0122x over previous
//
#include <hip/hip_runtime.h>
#include <hip/hip_bf16.h>
#include <cstdint>

#define TT 1024
#define BB 64
#define DD 1024
#define HH 30
#define G4 120

#define NPROD 64    // producer blocks (GEMM), t-striped rounds
#define NROUND 8    // tiles per producer block
#define GBLK 16     // tiles per flag group => 32 timesteps per group
#define NGRP 32     // number of flag groups

typedef __attribute__((ext_vector_type(8))) short short8;
typedef __attribute__((ext_vector_type(4))) float float4v;

// ---------------------------------------------------------------------------
__device__ __forceinline__ float frcp(float x) { return __builtin_amdgcn_rcpf(x); }
__device__ __forceinline__ float fsig(float x) { return frcp(1.0f + __expf(-x)); }
__device__ __forceinline__ float ftan(float x) {
    return 2.0f * frcp(1.0f + __expf(-2.0f * x)) - 1.0f;
}
__device__ __forceinline__ float bcast(float v, int l) {
    return __int_as_float(__builtin_amdgcn_readlane(__float_as_int(v), l));
}
__device__ __forceinline__ unsigned short bf16_rne(float f) {
    unsigned u = __float_as_uint(f);
    return (unsigned short)((u + 0x7FFFu + ((u >> 16) & 1u)) >> 16);
}

// ---------------------------------------------------------------------------
// Prep: pack W_ih0 into MFMA B-fragment order (split bf16 hi/lo), combine
// layer-0 biases, zero the producer-consumer flags.
__global__ void prep_kernel(const float* __restrict__ Wih0,
                            const float* __restrict__ bih0,
                            const float* __restrict__ bhh0,
                            unsigned short* __restrict__ Bhi,
                            unsigned short* __restrict__ Blo,
                            float* __restrict__ bias0,
                            unsigned* __restrict__ cnt) {
    int idx = blockIdx.x * 256 + threadIdx.x;   // 0..16383
    int l  = idx & 63;
    int kc = (idx >> 6) & 31;
    int nt = idx >> 11;
    int n = nt * 16 + (l & 15);
    int kb = kc * 32 + (l >> 4) * 8;
    size_t o = (size_t)idx * 8;
#pragma unroll
    for (int j = 0; j < 8; ++j) {
        float wv = (n < G4) ? Wih0[(size_t)n * DD + kb + j] : 0.0f;
        unsigned short hi = bf16_rne(wv);
        float fhi = __uint_as_float((unsigned)hi << 16);
        unsigned short lo = bf16_rne(wv - fhi);
        Bhi[o + j] = hi;
        Blo[o + j] = lo;
    }
    if (idx < 128) bias0[idx] = (idx < G4) ? (bih0[idx] + bhh0[idx]) : 0.0f;
    if (idx < NGRP) cnt[idx] = 0u;
}

// ---------------------------------------------------------------------------
// Fused producer-consumer kernel.
//  blocks [0, NPROD)          : GEMM producers. Block pb computes tiles
//                               pb, 64+pb, 128+pb, ... (t-ordered rounds).
//                               After each tile: fence + release-add on the
//                               tile's flag group (16 tiles = 32 timesteps).
//  blocks [NPROD, NPROD+BB)   : recurrence consumers (identical math to the
//                               previous lstm_rec), acquire-polling a flag
//                               once per 32 steps before prefetching xgp.
// No deadlock: producers never wait; consumers wait only on producers.
__global__ __launch_bounds__(256, 2) void fused_fwd(
    const float* __restrict__ x, const unsigned short* __restrict__ Bhi,
    const unsigned short* __restrict__ Blo, const float* __restrict__ bias0,
    float* __restrict__ xgp, const float* __restrict__ Whh0,
    const float* __restrict__ Wih1, const float* __restrict__ Whh1,
    const float* __restrict__ bih1, const float* __restrict__ bhh1,
    float* __restrict__ h2buf, unsigned* __restrict__ cnt) {

    __shared__ float2 pg[2][64];   // recurrence layer-1 partial-gate ring
    const int tid = threadIdx.x;

    if (blockIdx.x < NPROD) {
        // ================= producer: xg = x @ Wih0^T (+bias) =================
        const int pb = blockIdx.x;
        const int w = tid >> 6;
        const int l = tid & 63;
        const int lm = l & 15, lq = l >> 4;

        for (int r = 0; r < NROUND; ++r) {
            const int tile = r * NPROD + pb;          // 0..511, t-pair index
            const int r0 = tile * 128 + w * 32;

            float4v acc[2][8];
#pragma unroll
            for (int mt = 0; mt < 2; ++mt)
#pragma unroll
                for (int nt = 0; nt < 8; ++nt) acc[mt][nt] = (float4v)0.0f;

            const float* aptr[2];
            aptr[0] = x + (size_t)(r0 + lm) * DD + lq * 8;
            aptr[1] = x + (size_t)(r0 + 16 + lm) * DD + lq * 8;

            float4 pa[2][2];
#pragma unroll
            for (int mt = 0; mt < 2; ++mt) {
                pa[mt][0] = *(const float4*)(aptr[mt]);
                pa[mt][1] = *(const float4*)(aptr[mt] + 4);
            }

            for (int kc = 0; kc < 32; ++kc) {
                short8 ahi[2], alo[2];
#pragma unroll
                for (int mt = 0; mt < 2; ++mt) {
                    float f[8] = {pa[mt][0].x, pa[mt][0].y, pa[mt][0].z, pa[mt][0].w,
                                  pa[mt][1].x, pa[mt][1].y, pa[mt][1].z, pa[mt][1].w};
#pragma unroll
                    for (int i = 0; i < 8; ++i) {
                        unsigned ub = __float_as_uint(f[i]);
                        ahi[mt][i] = (short)(ub >> 16);
                        float fr = f[i] - __uint_as_float(ub & 0xFFFF0000u);
                        alo[mt][i] = (short)(__float_as_uint(fr) >> 16);
                    }
                }
                if (kc + 1 < 32) {
                    const int ko = (kc + 1) * 32;
#pragma unroll
                    for (int mt = 0; mt < 2; ++mt) {
                        pa[mt][0] = *(const float4*)(aptr[mt] + ko);
                        pa[mt][1] = *(const float4*)(aptr[mt] + ko + 4);
                    }
                }
#pragma unroll
                for (int nt = 0; nt < 8; ++nt) {
                    const size_t bo = ((size_t)(nt * 32 + kc) * 64 + l) * 8;
                    short8 bh = *(const short8*)(Bhi + bo);
                    short8 bl = *(const short8*)(Blo + bo);
                    acc[0][nt] = __builtin_amdgcn_mfma_f32_16x16x32_bf16(ahi[0], bh, acc[0][nt], 0, 0, 0);
                    acc[1][nt] = __builtin_amdgcn_mfma_f32_16x16x32_bf16(ahi[1], bh, acc[1][nt], 0, 0, 0);
                    acc[0][nt] = __builtin_amdgcn_mfma_f32_16x16x32_bf16(alo[0], bh, acc[0][nt], 0, 0, 0);
                    acc[1][nt] = __builtin_amdgcn_mfma_f32_16x16x32_bf16(alo[1], bh, acc[1][nt], 0, 0, 0);
                    acc[0][nt] = __builtin_amdgcn_mfma_f32_16x16x32_bf16(ahi[0], bl, acc[0][nt], 0, 0, 0);
                    acc[1][nt] = __builtin_amdgcn_mfma_f32_16x16x32_bf16(ahi[1], bl, acc[1][nt], 0, 0, 0);
                }
            }

            // epilogue: C/D layout col=lane&15, row=quad*4+reg. Permuted store.
#pragma unroll
            for (int nt = 0; nt < 8; ++nt) {
                const int g = nt * 16 + lm;
                if (g < G4) {
                    const int gm = g % 60;
                    const int lane_t = (gm < HH) ? gm : (32 + gm - HH);
                    const int slot = g / 60;
                    const float bb = bias0[g];
#pragma unroll
                    for (int mt = 0; mt < 2; ++mt)
#pragma unroll
                        for (int i = 0; i < 4; ++i) {
                            const size_t row = r0 + mt * 16 + lq * 4 + i;
                            xgp[(row * 64 + lane_t) * 2 + slot] = acc[mt][nt][i] + bb;
                        }
                }
            }
            __syncthreads();   // all stores of this tile drained (vmcnt before barrier)
            if (tid == 0) {
                __threadfence();
                __hip_atomic_fetch_add(&cnt[tile >> 4], 1u, __ATOMIC_RELEASE,
                                       __HIP_MEMORY_SCOPE_AGENT);
            }
        }
        return;
    }

    // ================= consumer: two-layer LSTM recurrence =================
    const int wv = tid >> 6;      // waves 0,1 work; waves 2,3 only barrier
    const int l = tid & 63;
    const int b = blockIdx.x - NPROD;
    const int u = l & 31;
    const int half = l >> 5;
    const bool al = (u < HH);
    const int rlo = half * HH + (al ? u : 0);
    const int rhi = 60 + rlo;

    float wa[HH], wb[HH], wc[HH], wd[HH];
    float b1lo = 0.f, b1hi = 0.f;
    if (wv == 0) {
#pragma unroll
        for (int j = 0; j < HH; ++j) {
            wa[j] = al ? Whh0[rlo * HH + j] : 0.f;
            wb[j] = al ? Whh0[rhi * HH + j] : 0.f;
            wc[j] = al ? Wih1[rlo * HH + j] : 0.f;
            wd[j] = al ? Wih1[rhi * HH + j] : 0.f;
        }
        b1lo = al ? (bih1[rlo] + bhh1[rlo]) : 0.f;
        b1hi = al ? (bih1[rhi] + bhh1[rhi]) : 0.f;
    } else if (wv == 1) {
#pragma unroll
        for (int j = 0; j < HH; ++j) {
            wa[j] = al ? Whh1[rlo * HH + j] : 0.f;
            wb[j] = al ? Whh1[rhi * HH + j] : 0.f;
            wc[j] = 0.f; wd[j] = 0.f;
        }
    }

    float hstate = 0.f, cstate = 0.f;
    float hb[HH];
#pragma unroll
    for (int j = 0; j < HH; ++j) hb[j] = 0.f;

    const float2* xgptr = (const float2*)xgp + (size_t)b * 64 + l;
    float2 xq[4];
    unsigned next_g = 0;
    if (wv == 0) {
        // wait for group 0 (covers t = 0..31) before the prologue prefetch
        while (__hip_atomic_load(&cnt[0], __ATOMIC_ACQUIRE, __HIP_MEMORY_SCOPE_AGENT) < GBLK)
            __builtin_amdgcn_s_sleep(8);
        next_g = 1;
#pragma unroll
        for (int p = 0; p < 4; ++p) xq[p] = xgptr[(size_t)p * (BB * 64)];
    }

    for (int t = 0; t <= TT; ++t) {
        if (wv == 0) {
            if (t < TT) {
                float2 xw = xq[t & 3];
                const int tn = (t + 4 < TT) ? t + 4 : TT - 1;
                const unsigned gneed = (unsigned)(tn >> 5);
                if (gneed >= next_g) {
                    while (__hip_atomic_load(&cnt[gneed], __ATOMIC_ACQUIRE,
                                             __HIP_MEMORY_SCOPE_AGENT) < GBLK)
                        __builtin_amdgcn_s_sleep(8);
                    next_g = gneed + 1;
                }
                xq[t & 3] = xgptr[(size_t)tn * (BB * 64)];

                // layer-0 gate dot (hb = h1 broadcasts from prev step)
                float aA = xw.x, aB = 0.f, cA = xw.y, cB = 0.f;
#pragma unroll
                for (int j = 0; j < HH; j += 2) {
                    aA = fmaf(wa[j], hb[j], aA);
                    cA = fmaf(wb[j], hb[j], cA);
                    aB = fmaf(wa[j + 1], hb[j + 1], aB);
                    cB = fmaf(wb[j + 1], hb[j + 1], cB);
                }
                float alo = aA + aB, ahi = cA + cB;
                float plo = __shfl_xor(alo, 32, 64);
                float phi = __shfl_xor(ahi, 32, 64);
                float ipre = half ? plo : alo;
                float fpre = half ? alo : plo;
                float gpre = half ? phi : ahi;
                float opre = half ? ahi : phi;
                cstate = fsig(fpre) * cstate + fsig(ipre) * ftan(gpre);
                hstate = fsig(opre) * ftan(cstate);
#pragma unroll
                for (int j = 0; j < HH; ++j) hb[j] = bcast(hstate, j);

                // layer-1 input partial: bias1 + Wih1 . h1(t)
                float zA = b1lo, zB = 0.f, yA = b1hi, yB = 0.f;
#pragma unroll
                for (int j = 0; j < HH; j += 2) {
                    zA = fmaf(wc[j], hb[j], zA);
                    yA = fmaf(wd[j], hb[j], yA);
                    zB = fmaf(wc[j + 1], hb[j + 1], zB);
                    yB = fmaf(wd[j + 1], hb[j + 1], yB);
                }
                pg[t & 1][l] = make_float2(zA + zB, yA + yB);
            }
        } else if (wv == 1) {
            if (t > 0) {
                const int s = t - 1;
                float2 part = pg[s & 1][l];
                float zA = part.x, zB = 0.f, yA = part.y, yB = 0.f;
#pragma unroll
                for (int j = 0; j < HH; j += 2) {
                    zA = fmaf(wa[j], hb[j], zA);       // Whh1 . h2(s-1)
                    yA = fmaf(wb[j], hb[j], yA);
                    zB = fmaf(wa[j + 1], hb[j + 1], zB);
                    yB = fmaf(wb[j + 1], hb[j + 1], yB);
                }
                float zlo = zA + zB, zhi = yA + yB;
                float qlo = __shfl_xor(zlo, 32, 64);
                float qhi = __shfl_xor(zhi, 32, 64);
                float ipre = half ? qlo : zlo;
                float fpre = half ? zlo : qlo;
                float gpre = half ? qhi : zhi;
                float opre = half ? zhi : qhi;
                cstate = fsig(fpre) * cstate + fsig(ipre) * ftan(gpre);
                hstate = fsig(opre) * ftan(cstate);
#pragma unroll
                for (int j = 0; j < HH; ++j) hb[j] = bcast(hstate, j);
                if (l < HH) h2buf[((size_t)s * BB + b) * 32 + l] = hstate;
            }
        }
        __syncthreads();
    }
}

// ---------------------------------------------------------------------------
// Output projection: out[t,b] = h2buf[t,b,:] . Wout + bout
__global__ __launch_bounds__(256) void out_proj(
    const float* __restrict__ h2buf, const float* __restrict__ Wout,
    const float* __restrict__ bout, float* __restrict__ out) {
    __shared__ float wos[32];
    if (threadIdx.x < 32)
        wos[threadIdx.x] = (threadIdx.x < HH) ? Wout[threadIdx.x] : 0.0f;
    __syncthreads();
    const int idx = blockIdx.x * 256 + threadIdx.x;   // 0..65535
    const float4* hp = (const float4*)(h2buf + (size_t)idx * 32);
    float s0 = 0.f, s1 = 0.f;
#pragma unroll
    for (int q = 0; q < 8; ++q) {
        float4 h = hp[q];
        s0 = fmaf(h.x, wos[q * 4 + 0], s0);
        s1 = fmaf(h.y, wos[q * 4 + 1], s1);
        s0 = fmaf(h.z, wos[q * 4 + 2], s0);
        s1 = fmaf(h.w, wos[q * 4 + 3], s1);
    }
    out[idx] = s0 + s1 + bout[0];
}

// ---------------------------------------------------------------------------
extern "C" void kernel_launch(void* const* d_in, const int* in_sizes, int n_in,
                              void* d_out, int out_size, void* d_ws, size_t ws_size,
                              hipStream_t stream) {
    const float* x    = (const float*)d_in[0];
    const float* Wih0 = (const float*)d_in[1];
    const float* Whh0 = (const float*)d_in[2];
    const float* bih0 = (const float*)d_in[3];
    const float* bhh0 = (const float*)d_in[4];
    const float* Wih1 = (const float*)d_in[5];
    const float* Whh1 = (const float*)d_in[6];
    const float* bih1 = (const float*)d_in[7];
    const float* bhh1 = (const float*)d_in[8];
    const float* Wout = (const float*)d_in[9];
    const float* bout = (const float*)d_in[10];
    float* out = (float*)d_out;

    char* ws = (char*)d_ws;
    unsigned short* Bhi = (unsigned short*)ws;                 // 256 KB
    unsigned short* Blo = (unsigned short*)(ws + 262144);      // 256 KB
    float* bias0 = (float*)(ws + 524288);                      // 512 B
    unsigned* cnt = (unsigned*)(ws + 524800);                  // 128 B flags
    float* xgp   = (float*)(ws + 1024 * 1024);                 // 33.55 MB
    float* h2buf = (float*)(ws + 36 * 1024 * 1024);            // 8.39 MB

    prep_kernel<<<64, 256, 0, stream>>>(Wih0, bih0, bhh0, Bhi, Blo, bias0, cnt);
    fused_fwd<<<NPROD + BB, 256, 0, stream>>>(x, Bhi, Blo, bias0, xgp,
                                              Whh0, Wih1, Whh1, bih1, bhh1,
                                              h2buf, cnt);
    out_proj<<<256, 256, 0, stream>>>(h2buf, Wout, bout, out);
}

// Round 2
// 1051.590 us; speedup vs baseline: 1.0135x; 1.0013x over previous
//
#include <hip/hip_runtime.h>
#include <hip/hip_bf16.h>
#include <cstdint>

#define TT 1024
#define BB 64
#define DD 1024
#define HH 30
#define G4 120

#define NPROD 64    // producer blocks (GEMM), t-striped rounds
#define NROUND 8    // tiles per producer block
#define GBLK 16     // tiles per flag group => 32 timesteps per group
#define NGRP 32     // number of flag groups

typedef __attribute__((ext_vector_type(8))) short short8;
typedef __attribute__((ext_vector_type(4))) float float4v;

// ---------------------------------------------------------------------------
__device__ __forceinline__ float frcp(float x) { return __builtin_amdgcn_rcpf(x); }
__device__ __forceinline__ float fsig(float x) { return frcp(1.0f + __expf(-x)); }
__device__ __forceinline__ float ftan(float x) {
    return 2.0f * frcp(1.0f + __expf(-2.0f * x)) - 1.0f;
}
__device__ __forceinline__ float bcast(float v, int l) {
    return __int_as_float(__builtin_amdgcn_readlane(__float_as_int(v), l));
}
__device__ __forceinline__ unsigned short bf16_rne(float f) {
    unsigned u = __float_as_uint(f);
    return (unsigned short)((u + 0x7FFFu + ((u >> 16) & 1u)) >> 16);
}
// Raw workgroup barrier: orders LDS ops (lgkmcnt drain) but does NOT drain
// vmcnt — in-flight global prefetches/stores survive across the barrier.
// "memory" clobber pins the pg LDS write/read on the correct side.
__device__ __forceinline__ void barrier_lds_only() {
    asm volatile("s_waitcnt lgkmcnt(0)\n\ts_barrier" ::: "memory");
}

// ---------------------------------------------------------------------------
// Prep: pack W_ih0 into MFMA B-fragment order (split bf16 hi/lo), combine
// layer-0 biases, zero the producer-consumer flags.
__global__ void prep_kernel(const float* __restrict__ Wih0,
                            const float* __restrict__ bih0,
                            const float* __restrict__ bhh0,
                            unsigned short* __restrict__ Bhi,
                            unsigned short* __restrict__ Blo,
                            float* __restrict__ bias0,
                            unsigned* __restrict__ cnt) {
    int idx = blockIdx.x * 256 + threadIdx.x;   // 0..16383
    int l  = idx & 63;
    int kc = (idx >> 6) & 31;
    int nt = idx >> 11;
    int n = nt * 16 + (l & 15);
    int kb = kc * 32 + (l >> 4) * 8;
    size_t o = (size_t)idx * 8;
#pragma unroll
    for (int j = 0; j < 8; ++j) {
        float wv = (n < G4) ? Wih0[(size_t)n * DD + kb + j] : 0.0f;
        unsigned short hi = bf16_rne(wv);
        float fhi = __uint_as_float((unsigned)hi << 16);
        unsigned short lo = bf16_rne(wv - fhi);
        Bhi[o + j] = hi;
        Blo[o + j] = lo;
    }
    if (idx < 128) bias0[idx] = (idx < G4) ? (bih0[idx] + bhh0[idx]) : 0.0f;
    if (idx < NGRP) cnt[idx] = 0u;
}

// ---------------------------------------------------------------------------
// Fused producer-consumer kernel.
//  blocks [0, NPROD)          : GEMM producers. Block pb computes tiles
//                               pb, 64+pb, 128+pb, ... (t-ordered rounds).
//                               After each tile: fence + release-add on the
//                               tile's flag group (16 tiles = 32 timesteps).
//  blocks [NPROD, NPROD+BB)   : recurrence consumers, acquire-polling a flag
//                               once per 32 steps before prefetching xgp.
//                               Per-step sync is a raw lgkmcnt-only barrier so
//                               the xq prefetch / h2 store pipeline across it.
// No deadlock: producers never wait; consumers wait only on producers.
__global__ __launch_bounds__(256, 2) void fused_fwd(
    const float* __restrict__ x, const unsigned short* __restrict__ Bhi,
    const unsigned short* __restrict__ Blo, const float* __restrict__ bias0,
    float* __restrict__ xgp, const float* __restrict__ Whh0,
    const float* __restrict__ Wih1, const float* __restrict__ Whh1,
    const float* __restrict__ bih1, const float* __restrict__ bhh1,
    float* __restrict__ h2buf, unsigned* __restrict__ cnt) {

    __shared__ float2 pg[2][64];   // recurrence layer-1 partial-gate ring
    const int tid = threadIdx.x;

    if (blockIdx.x < NPROD) {
        // ================= producer: xg = x @ Wih0^T (+bias) =================
        const int pb = blockIdx.x;
        const int w = tid >> 6;
        const int l = tid & 63;
        const int lm = l & 15, lq = l >> 4;

        for (int r = 0; r < NROUND; ++r) {
            const int tile = r * NPROD + pb;          // 0..511, t-pair index
            const int r0 = tile * 128 + w * 32;

            float4v acc[2][8];
#pragma unroll
            for (int mt = 0; mt < 2; ++mt)
#pragma unroll
                for (int nt = 0; nt < 8; ++nt) acc[mt][nt] = (float4v)0.0f;

            const float* aptr[2];
            aptr[0] = x + (size_t)(r0 + lm) * DD + lq * 8;
            aptr[1] = x + (size_t)(r0 + 16 + lm) * DD + lq * 8;

            float4 pa[2][2];
#pragma unroll
            for (int mt = 0; mt < 2; ++mt) {
                pa[mt][0] = *(const float4*)(aptr[mt]);
                pa[mt][1] = *(const float4*)(aptr[mt] + 4);
            }

            for (int kc = 0; kc < 32; ++kc) {
                short8 ahi[2], alo[2];
#pragma unroll
                for (int mt = 0; mt < 2; ++mt) {
                    float f[8] = {pa[mt][0].x, pa[mt][0].y, pa[mt][0].z, pa[mt][0].w,
                                  pa[mt][1].x, pa[mt][1].y, pa[mt][1].z, pa[mt][1].w};
#pragma unroll
                    for (int i = 0; i < 8; ++i) {
                        unsigned ub = __float_as_uint(f[i]);
                        ahi[mt][i] = (short)(ub >> 16);
                        float fr = f[i] - __uint_as_float(ub & 0xFFFF0000u);
                        alo[mt][i] = (short)(__float_as_uint(fr) >> 16);
                    }
                }
                if (kc + 1 < 32) {
                    const int ko = (kc + 1) * 32;
#pragma unroll
                    for (int mt = 0; mt < 2; ++mt) {
                        pa[mt][0] = *(const float4*)(aptr[mt] + ko);
                        pa[mt][1] = *(const float4*)(aptr[mt] + ko + 4);
                    }
                }
#pragma unroll
                for (int nt = 0; nt < 8; ++nt) {
                    const size_t bo = ((size_t)(nt * 32 + kc) * 64 + l) * 8;
                    short8 bh = *(const short8*)(Bhi + bo);
                    short8 bl = *(const short8*)(Blo + bo);
                    acc[0][nt] = __builtin_amdgcn_mfma_f32_16x16x32_bf16(ahi[0], bh, acc[0][nt], 0, 0, 0);
                    acc[1][nt] = __builtin_amdgcn_mfma_f32_16x16x32_bf16(ahi[1], bh, acc[1][nt], 0, 0, 0);
                    acc[0][nt] = __builtin_amdgcn_mfma_f32_16x16x32_bf16(alo[0], bh, acc[0][nt], 0, 0, 0);
                    acc[1][nt] = __builtin_amdgcn_mfma_f32_16x16x32_bf16(alo[1], bh, acc[1][nt], 0, 0, 0);
                    acc[0][nt] = __builtin_amdgcn_mfma_f32_16x16x32_bf16(ahi[0], bl, acc[0][nt], 0, 0, 0);
                    acc[1][nt] = __builtin_amdgcn_mfma_f32_16x16x32_bf16(ahi[1], bl, acc[1][nt], 0, 0, 0);
                }
            }

            // epilogue: C/D layout col=lane&15, row=quad*4+reg. Permuted store.
#pragma unroll
            for (int nt = 0; nt < 8; ++nt) {
                const int g = nt * 16 + lm;
                if (g < G4) {
                    const int gm = g % 60;
                    const int lane_t = (gm < HH) ? gm : (32 + gm - HH);
                    const int slot = g / 60;
                    const float bb = bias0[g];
#pragma unroll
                    for (int mt = 0; mt < 2; ++mt)
#pragma unroll
                        for (int i = 0; i < 4; ++i) {
                            const size_t row = r0 + mt * 16 + lq * 4 + i;
                            xgp[(row * 64 + lane_t) * 2 + slot] = acc[mt][nt][i] + bb;
                        }
                }
            }
            __syncthreads();   // full drain: stores done before the release add
            if (tid == 0) {
                __threadfence();
                __hip_atomic_fetch_add(&cnt[tile >> 4], 1u, __ATOMIC_RELEASE,
                                       __HIP_MEMORY_SCOPE_AGENT);
            }
        }
        return;
    }

    // ================= consumer: two-layer LSTM recurrence =================
    const int wv = tid >> 6;      // waves 0,1 work; waves 2,3 only barrier
    const int l = tid & 63;
    const int b = blockIdx.x - NPROD;
    const int u = l & 31;
    const int half = l >> 5;
    const bool al = (u < HH);
    const int rlo = half * HH + (al ? u : 0);
    const int rhi = 60 + rlo;

    float wa[HH], wb[HH], wc[HH], wd[HH];
    float b1lo = 0.f, b1hi = 0.f;
    if (wv == 0) {
#pragma unroll
        for (int j = 0; j < HH; ++j) {
            wa[j] = al ? Whh0[rlo * HH + j] : 0.f;
            wb[j] = al ? Whh0[rhi * HH + j] : 0.f;
            wc[j] = al ? Wih1[rlo * HH + j] : 0.f;
            wd[j] = al ? Wih1[rhi * HH + j] : 0.f;
        }
        b1lo = al ? (bih1[rlo] + bhh1[rlo]) : 0.f;
        b1hi = al ? (bih1[rhi] + bhh1[rhi]) : 0.f;
    } else if (wv == 1) {
#pragma unroll
        for (int j = 0; j < HH; ++j) {
            wa[j] = al ? Whh1[rlo * HH + j] : 0.f;
            wb[j] = al ? Whh1[rhi * HH + j] : 0.f;
            wc[j] = 0.f; wd[j] = 0.f;
        }
    }

    float hstate = 0.f, cstate = 0.f;
    float hb[HH];
#pragma unroll
    for (int j = 0; j < HH; ++j) hb[j] = 0.f;

    const float2* xgptr = (const float2*)xgp + (size_t)b * 64 + l;
    float2 xq[4];
    unsigned next_g = 0;
    if (wv == 0) {
        // wait for group 0 (covers t = 0..31) before the prologue prefetch
        while (__hip_atomic_load(&cnt[0], __ATOMIC_ACQUIRE, __HIP_MEMORY_SCOPE_AGENT) < GBLK)
            __builtin_amdgcn_s_sleep(8);
        next_g = 1;
#pragma unroll
        for (int p = 0; p < 4; ++p) xq[p] = xgptr[(size_t)p * (BB * 64)];
    }

    for (int t = 0; t <= TT; ++t) {
        if (wv == 0) {
            if (t < TT) {
                float2 xw = xq[t & 3];
                const int tn = (t + 4 < TT) ? t + 4 : TT - 1;
                const unsigned gneed = (unsigned)(tn >> 5);
                if (gneed >= next_g) {
                    while (__hip_atomic_load(&cnt[gneed], __ATOMIC_ACQUIRE,
                                             __HIP_MEMORY_SCOPE_AGENT) < GBLK)
                        __builtin_amdgcn_s_sleep(8);
                    next_g = gneed + 1;
                }
                xq[t & 3] = xgptr[(size_t)tn * (BB * 64)];

                // layer-0 gate dot (hb = h1 broadcasts from prev step)
                float aA = xw.x, aB = 0.f, cA = xw.y, cB = 0.f;
#pragma unroll
                for (int j = 0; j < HH; j += 2) {
                    aA = fmaf(wa[j], hb[j], aA);
                    cA = fmaf(wb[j], hb[j], cA);
                    aB = fmaf(wa[j + 1], hb[j + 1], aB);
                    cB = fmaf(wb[j + 1], hb[j + 1], cB);
                }
                float alo = aA + aB, ahi = cA + cB;
                float plo = __shfl_xor(alo, 32, 64);
                float phi = __shfl_xor(ahi, 32, 64);
                float ipre = half ? plo : alo;
                float fpre = half ? alo : plo;
                float gpre = half ? phi : ahi;
                float opre = half ? ahi : phi;
                cstate = fsig(fpre) * cstate + fsig(ipre) * ftan(gpre);
                hstate = fsig(opre) * ftan(cstate);
#pragma unroll
                for (int j = 0; j < HH; ++j) hb[j] = bcast(hstate, j);

                // layer-1 input partial: bias1 + Wih1 . h1(t)
                float zA = b1lo, zB = 0.f, yA = b1hi, yB = 0.f;
#pragma unroll
                for (int j = 0; j < HH; j += 2) {
                    zA = fmaf(wc[j], hb[j], zA);
                    yA = fmaf(wd[j], hb[j], yA);
                    zB = fmaf(wc[j + 1], hb[j + 1], zB);
                    yB = fmaf(wd[j + 1], hb[j + 1], yB);
                }
                pg[t & 1][l] = make_float2(zA + zB, yA + yB);
            }
        } else if (wv == 1) {
            if (t > 0) {
                const int s = t - 1;
                float2 part = pg[s & 1][l];
                float zA = part.x, zB = 0.f, yA = part.y, yB = 0.f;
#pragma unroll
                for (int j = 0; j < HH; j += 2) {
                    zA = fmaf(wa[j], hb[j], zA);       // Whh1 . h2(s-1)
                    yA = fmaf(wb[j], hb[j], yA);
                    zB = fmaf(wa[j + 1], hb[j + 1], zB);
                    yB = fmaf(wb[j + 1], hb[j + 1], yB);
                }
                float zlo = zA + zB, zhi = yA + yB;
                float qlo = __shfl_xor(zlo, 32, 64);
                float qhi = __shfl_xor(zhi, 32, 64);
                float ipre = half ? qlo : zlo;
                float fpre = half ? zlo : qlo;
                float gpre = half ? qhi : zhi;
                float opre = half ? zhi : qhi;
                cstate = fsig(fpre) * cstate + fsig(ipre) * ftan(gpre);
                hstate = fsig(opre) * ftan(cstate);
#pragma unroll
                for (int j = 0; j < HH; ++j) hb[j] = bcast(hstate, j);
                if (l < HH) h2buf[((size_t)s * BB + b) * 32 + l] = hstate;
            }
        }
        // Raw barrier: LDS-ordered only; xq prefetch + h2 store stay in flight.
        barrier_lds_only();
    }
}

// ---------------------------------------------------------------------------
// Output projection: out[t,b] = h2buf[t,b,:] . Wout + bout
__global__ __launch_bounds__(256) void out_proj(
    const float* __restrict__ h2buf, const float* __restrict__ Wout,
    const float* __restrict__ bout, float* __restrict__ out) {
    __shared__ float wos[32];
    if (threadIdx.x < 32)
        wos[threadIdx.x] = (threadIdx.x < HH) ? Wout[threadIdx.x] : 0.0f;
    __syncthreads();
    const int idx = blockIdx.x * 256 + threadIdx.x;   // 0..65535
    const float4* hp = (const float4*)(h2buf + (size_t)idx * 32);
    float s0 = 0.f, s1 = 0.f;
#pragma unroll
    for (int q = 0; q < 8; ++q) {
        float4 h = hp[q];
        s0 = fmaf(h.x, wos[q * 4 + 0], s0);
        s1 = fmaf(h.y, wos[q * 4 + 1], s1);
        s0 = fmaf(h.z, wos[q * 4 + 2], s0);
        s1 = fmaf(h.w, wos[q * 4 + 3], s1);
    }
    out[idx] = s0 + s1 + bout[0];
}

// ---------------------------------------------------------------------------
extern "C" void kernel_launch(void* const* d_in, const int* in_sizes, int n_in,
                              void* d_out, int out_size, void* d_ws, size_t ws_size,
                              hipStream_t stream) {
    const float* x    = (const float*)d_in[0];
    const float* Wih0 = (const float*)d_in[1];
    const float* Whh0 = (const float*)d_in[2];
    const float* bih0 = (const float*)d_in[3];
    const float* bhh0 = (const float*)d_in[4];
    const float* Wih1 = (const float*)d_in[5];
    const float* Whh1 = (const float*)d_in[6];
    const float* bih1 = (const float*)d_in[7];
    const float* bhh1 = (const float*)d_in[8];
    const float* Wout = (const float*)d_in[9];
    const float* bout = (const float*)d_in[10];
    float* out = (float*)d_out;

    char* ws = (char*)d_ws;
    unsigned short* Bhi = (unsigned short*)ws;                 // 256 KB
    unsigned short* Blo = (unsigned short*)(ws + 262144);      // 256 KB
    float* bias0 = (float*)(ws + 524288);                      // 512 B
    unsigned* cnt = (unsigned*)(ws + 524800);                  // 128 B flags
    float* xgp   = (float*)(ws + 1024 * 1024);                 // 33.55 MB
    float* h2buf = (float*)(ws + 36 * 1024 * 1024);            // 8.39 MB

    prep_kernel<<<64, 256, 0, stream>>>(Wih0, bih0, bhh0, Bhi, Blo, bias0, cnt);
    fused_fwd<<<NPROD + BB, 256, 0, stream>>>(x, Bhi, Blo, bias0, xgp,
                                              Whh0, Wih1, Whh1, bih1, bhh1,
                                              h2buf, cnt);
    out_proj<<<256, 256, 0, stream>>>(h2buf, Wout, bout, out);
}